// Round 1
// baseline (45.481 us; speedup 1.0000x reference)
//
#include <hip/hip_runtime.h>

// LengthRegulator: B=32, L=256, H=384, T(MAX_WAVE)=2048
// out0: (B, H, T) float32 = gathered^T ; out1: (B, T) float32 mask
constexpr int Lc = 256;
constexpr int Hc = 384;
constexpr int Tc = 2048;
constexpr int Bc = 32;
constexpr int T_PER_BLOCK = 1024;  // 256 threads x 4 t each (float4 stores)
constexpr int H_PER_BLOCK = 48;    // 384 / 8 h-tiles

__global__ __launch_bounds__(256) void lr_expand_kernel(
    const float* __restrict__ enc,   // (B, L, H)
    const int*   __restrict__ dur,   // (B, L)
    float*       __restrict__ out,   // (B, H, T)
    float*       __restrict__ mask)  // (B, T)
{
    const int tid = threadIdx.x;          // 0..255
    const int b   = blockIdx.z;

    // ---- per-batch inclusive cumsum of durations in LDS (Hillis-Steele) ----
    __shared__ int s_csum[Lc];
    s_csum[tid] = dur[b * Lc + tid];
    __syncthreads();
#pragma unroll
    for (int off = 1; off < Lc; off <<= 1) {
        int v = (tid >= off) ? s_csum[tid - off] : 0;
        __syncthreads();
        s_csum[tid] += v;
        __syncthreads();
    }
    const int total = s_csum[Lc - 1];

    // ---- each thread owns 4 consecutive t values ----
    const int tbase = blockIdx.x * T_PER_BLOCK + tid * 4;

    int   rowoff[4];   // safe_idx * Hc
    float mflag[4];    // 1.0 if valid else 0.0

    {
        // searchsorted(csum, t, side='right') = first i with csum[i] > t
        int lo = 0, hi = Lc;
        while (lo < hi) {
            int mid = (lo + hi) >> 1;
            if (s_csum[mid] <= tbase) lo = mid + 1; else hi = mid;
        }
        int cur = lo;
#pragma unroll
        for (int k = 0; k < 4; ++k) {
            const int tt = tbase + k;
            while (cur < Lc && s_csum[cur] <= tt) cur++;
            const int safe = (cur < Lc - 1) ? cur : (Lc - 1);
            rowoff[k] = safe * Hc;
            mflag[k]  = (tt < total) ? 1.0f : 0.0f;
        }
    }

    // ---- gather + transpose-write: out[b][h][t] = enc[b][idx[t]][h] * m ----
    const float* encb = enc + (size_t)b * (Lc * Hc);
    float*       outb = out + (size_t)b * (Hc * Tc) + tbase;
    const int h0 = blockIdx.y * H_PER_BLOCK;

    for (int hh = 0; hh < H_PER_BLOCK; ++hh) {
        const int h = h0 + hh;
        float4 r;
        r.x = encb[rowoff[0] + h] * mflag[0];
        r.y = encb[rowoff[1] + h] * mflag[1];
        r.z = encb[rowoff[2] + h] * mflag[2];
        r.w = encb[rowoff[3] + h] * mflag[3];
        *reinterpret_cast<float4*>(outb + (size_t)h * Tc) = r;
    }

    // ---- mask (one h-tile writes it) ----
    if (blockIdx.y == 0) {
        float4 m;
        m.x = mflag[0]; m.y = mflag[1]; m.z = mflag[2]; m.w = mflag[3];
        *reinterpret_cast<float4*>(mask + (size_t)b * Tc + tbase) = m;
    }
}

extern "C" void kernel_launch(void* const* d_in, const int* in_sizes, int n_in,
                              void* d_out, int out_size, void* d_ws, size_t ws_size,
                              hipStream_t stream) {
    const float* enc = (const float*)d_in[0];   // (32, 256, 384) f32
    const int*   dur = (const int*)d_in[1];     // (32, 256) i32

    float* out  = (float*)d_out;                      // (32, 384, 2048)
    float* mask = out + (size_t)Bc * Hc * Tc;         // (32, 2048)

    dim3 grid(Tc / T_PER_BLOCK, Hc / H_PER_BLOCK, Bc); // (2, 8, 32) = 512 blocks
    dim3 block(256);
    lr_expand_kernel<<<grid, block, 0, stream>>>(enc, dur, out, mask);
}

// Round 2
// 29.045 us; speedup vs baseline: 1.5659x; 1.5659x over previous
//
#include <hip/hip_runtime.h>

// LengthRegulator: B=32, L=256, H=384, T(MAX_WAVE)=2048
// out0: (B, H, T) float32 = gathered^T ; out1: (B, T) float32 mask
constexpr int Lc = 256;
constexpr int Hc = 384;
constexpr int Tc = 2048;
constexpr int Bc = 32;
constexpr int T_PER_BLOCK = 1024;  // 256 threads x 4 t each (float4 stores)
constexpr int H_PER_BLOCK = 12;    // 384 / 32 h-tiles -> 2048 blocks (32 waves/CU)

__global__ __launch_bounds__(256) void lr_expand_kernel(
    const float* __restrict__ enc,   // (B, L, H)
    const int*   __restrict__ dur,   // (B, L)
    float*       __restrict__ out,   // (B, H, T)
    float*       __restrict__ mask)  // (B, T)
{
    const int tid = threadIdx.x;          // 0..255
    const int b   = blockIdx.z;

    // ---- per-batch inclusive cumsum of durations in LDS (Hillis-Steele) ----
    __shared__ int s_csum[Lc];
    s_csum[tid] = dur[b * Lc + tid];
    __syncthreads();
#pragma unroll
    for (int off = 1; off < Lc; off <<= 1) {
        int v = (tid >= off) ? s_csum[tid - off] : 0;
        __syncthreads();
        s_csum[tid] += v;
        __syncthreads();
    }
    const int total = s_csum[Lc - 1];

    // ---- each thread owns 4 consecutive t values ----
    const int tbase = blockIdx.x * T_PER_BLOCK + tid * 4;

    int   rowoff[4];   // safe_idx * Hc
    float mflag[4];    // 1.0 if valid else 0.0

    {
        // searchsorted(csum, t, side='right') = first i with csum[i] > t
        int lo = 0, hi = Lc;
        while (lo < hi) {
            int mid = (lo + hi) >> 1;
            if (s_csum[mid] <= tbase) lo = mid + 1; else hi = mid;
        }
        int cur = lo;
#pragma unroll
        for (int k = 0; k < 4; ++k) {
            const int tt = tbase + k;
            while (cur < Lc && s_csum[cur] <= tt) cur++;
            const int safe = (cur < Lc - 1) ? cur : (Lc - 1);
            rowoff[k] = safe * Hc;
            mflag[k]  = (tt < total) ? 1.0f : 0.0f;
        }
    }

    // ---- gather + transpose-write: out[b][h][t] = enc[b][idx[t]][h] * m ----
    const float* encb = enc + (size_t)b * (Lc * Hc);
    float*       outb = out + (size_t)b * (Hc * Tc) + tbase;
    const int h0 = blockIdx.y * H_PER_BLOCK;

    // Fully unrolled: issue all 48 gather loads early (ILP), then stores.
    float4 r[H_PER_BLOCK];
#pragma unroll
    for (int hh = 0; hh < H_PER_BLOCK; ++hh) {
        const int h = h0 + hh;
        r[hh].x = encb[rowoff[0] + h];
        r[hh].y = encb[rowoff[1] + h];
        r[hh].z = encb[rowoff[2] + h];
        r[hh].w = encb[rowoff[3] + h];
    }
#pragma unroll
    for (int hh = 0; hh < H_PER_BLOCK; ++hh) {
        const int h = h0 + hh;
        float4 v;
        v.x = r[hh].x * mflag[0];
        v.y = r[hh].y * mflag[1];
        v.z = r[hh].z * mflag[2];
        v.w = r[hh].w * mflag[3];
        *reinterpret_cast<float4*>(outb + (size_t)h * Tc) = v;
    }

    // ---- mask (one h-tile writes it) ----
    if (blockIdx.y == 0) {
        float4 m;
        m.x = mflag[0]; m.y = mflag[1]; m.z = mflag[2]; m.w = mflag[3];
        *reinterpret_cast<float4*>(mask + (size_t)b * Tc + tbase) = m;
    }
}

extern "C" void kernel_launch(void* const* d_in, const int* in_sizes, int n_in,
                              void* d_out, int out_size, void* d_ws, size_t ws_size,
                              hipStream_t stream) {
    const float* enc = (const float*)d_in[0];   // (32, 256, 384) f32
    const int*   dur = (const int*)d_in[1];     // (32, 256) i32

    float* out  = (float*)d_out;                      // (32, 384, 2048)
    float* mask = out + (size_t)Bc * Hc * Tc;         // (32, 2048)

    dim3 grid(Tc / T_PER_BLOCK, Hc / H_PER_BLOCK, Bc); // (2, 32, 32) = 2048 blocks
    dim3 block(256);
    lr_expand_kernel<<<grid, block, 0, stream>>>(enc, dur, out, mask);
}

// Round 3
// 27.276 us; speedup vs baseline: 1.6674x; 1.0648x over previous
//
#include <hip/hip_runtime.h>

// LengthRegulator: B=32, L=256, H=384, T(MAX_WAVE)=2048
// out0: (B, H, T) float32 = gathered^T ; out1: (B, T) float32 mask
constexpr int Lc = 256;
constexpr int Hc = 384;
constexpr int Tc = 2048;
constexpr int Bc = 32;
constexpr int T_PER_BLOCK = 1024;  // 256 threads x 4 t each (float4 stores)
constexpr int H_TILE = 16;         // 384 / 16 = 24 h-tiles -> grid (2,24,32)=1536 blocks
constexpr int PADW = 17;           // LDS row stride (floats); 17 coprime 32 banks

__global__ __launch_bounds__(256) void lr_expand_kernel(
    const float* __restrict__ enc,   // (B, L, H)
    const int*   __restrict__ dur,   // (B, L)
    float*       __restrict__ out,   // (B, H, T)
    float*       __restrict__ mask)  // (B, T)
{
    const int tid = threadIdx.x;          // 0..255
    const int b   = blockIdx.z;
    const int h0  = blockIdx.y * H_TILE;

    __shared__ int   s_csum[Lc];
    __shared__ float s_enc[Lc * PADW];    // 256 x 16 tile, padded stride 17

    // ---- stage enc tile (rows 0..255, cols h0..h0+15) into LDS, coalesced ----
    // 4 threads per row, float4 each -> 64B contiguous per row per instr.
    {
        const float* encb = enc + (size_t)b * (Lc * Hc) + h0;
        const int r  = tid >> 2;          // 0..63
        const int c4 = (tid & 3) * 4;     // 0,4,8,12
#pragma unroll
        for (int it = 0; it < 4; ++it) {
            const int row = r + it * 64;
            float4 v = *reinterpret_cast<const float4*>(encb + (size_t)row * Hc + c4);
            float* dst = s_enc + row * PADW + c4;
            dst[0] = v.x; dst[1] = v.y; dst[2] = v.z; dst[3] = v.w;
        }
    }

    // ---- per-batch inclusive cumsum of durations (Hillis-Steele in LDS) ----
    s_csum[tid] = dur[b * Lc + tid];
    __syncthreads();
#pragma unroll
    for (int off = 1; off < Lc; off <<= 1) {
        int v = (tid >= off) ? s_csum[tid - off] : 0;
        __syncthreads();
        s_csum[tid] += v;
        __syncthreads();
    }
    const int total = s_csum[Lc - 1];

    // ---- each thread owns 4 consecutive t values ----
    const int tbase = blockIdx.x * T_PER_BLOCK + tid * 4;

    int   rowoff[4];   // safe_idx * PADW (LDS row offset)
    float mflag[4];    // 1.0 if valid else 0.0
    {
        // searchsorted(csum, t, side='right') = first i with csum[i] > t
        int lo = 0, hi = Lc;
        while (lo < hi) {
            int mid = (lo + hi) >> 1;
            if (s_csum[mid] <= tbase) lo = mid + 1; else hi = mid;
        }
        int cur = lo;
#pragma unroll
        for (int k = 0; k < 4; ++k) {
            const int tt = tbase + k;
            while (cur < Lc && s_csum[cur] <= tt) cur++;
            const int safe = (cur < Lc - 1) ? cur : (Lc - 1);
            rowoff[k] = safe * PADW;
            mflag[k]  = (tt < total) ? 1.0f : 0.0f;
        }
    }

    // ---- gather from LDS + transpose-write ----
    float* outb = out + (size_t)b * (Hc * Tc) + (size_t)h0 * Tc + tbase;
#pragma unroll
    for (int hh = 0; hh < H_TILE; ++hh) {
        float4 v;
        v.x = s_enc[rowoff[0] + hh] * mflag[0];
        v.y = s_enc[rowoff[1] + hh] * mflag[1];
        v.z = s_enc[rowoff[2] + hh] * mflag[2];
        v.w = s_enc[rowoff[3] + hh] * mflag[3];
        *reinterpret_cast<float4*>(outb + (size_t)hh * Tc) = v;
    }

    // ---- mask (one h-tile writes it) ----
    if (blockIdx.y == 0) {
        float4 m;
        m.x = mflag[0]; m.y = mflag[1]; m.z = mflag[2]; m.w = mflag[3];
        *reinterpret_cast<float4*>(mask + (size_t)b * Tc + tbase) = m;
    }
}

extern "C" void kernel_launch(void* const* d_in, const int* in_sizes, int n_in,
                              void* d_out, int out_size, void* d_ws, size_t ws_size,
                              hipStream_t stream) {
    const float* enc = (const float*)d_in[0];   // (32, 256, 384) f32
    const int*   dur = (const int*)d_in[1];     // (32, 256) i32

    float* out  = (float*)d_out;                      // (32, 384, 2048)
    float* mask = out + (size_t)Bc * Hc * Tc;         // (32, 2048)

    dim3 grid(Tc / T_PER_BLOCK, Hc / H_TILE, Bc);     // (2, 24, 32) = 1536 blocks
    dim3 block(256);
    lr_expand_kernel<<<grid, block, 0, stream>>>(enc, dur, out, mask);
}